// Round 6
// baseline (220.276 us; speedup 1.0000x reference)
//
#include <hip/hip_runtime.h>

#define D_MODEL 1024
#define D_FF    8192
#define N_ELEM  64
#define D1      128
#define BATCH   2048
#define B_T     8      // batch rows per block (main kernel)
#define NJT     8      // j tiles (== XCD count)
#define JT      16     // j per tile

typedef unsigned short u16;
typedef unsigned int   u32;
typedef _Float16 h2   __attribute__((ext_vector_type(2)));
typedef float    f32x4 __attribute__((ext_vector_type(4)));
typedef u32      u32x2 __attribute__((ext_vector_type(2)));

__device__ __forceinline__ h2 as_h2(u32 u) { union { u32 i; h2 h; } c; c.i = u; return c.h; }
__device__ __forceinline__ u32 pkh(float a, float b) {
    union { h2 h; u32 u; } c; c.h.x = (_Float16)a; c.h.y = (_Float16)b; return c.u;
}
__device__ __forceinline__ u16 f2h(float f) {
    union { _Float16 h; u16 u; } c; c.h = (_Float16)f; return c.u;
}
__device__ __forceinline__ f32x4 ntload4(const float* p) {
    return __builtin_nontemporal_load((const f32x4*)p);
}

// ---------------------------------------------------------------------------
// Prep A: transpose+cast w1 [d][j*64+e] (1024x8192 f32) -> w1h [j*64+e][d] f16
// ---------------------------------------------------------------------------
__global__ __launch_bounds__(256) void transpose_cast_w1(const float* __restrict__ w1,
                                                         u16* __restrict__ w1h) {
    __shared__ float tile[64][65];
    const int c0 = blockIdx.x * 64;
    const int d0 = blockIdx.y * 64;
    const int tx = threadIdx.x & 15;
    const int ty = threadIdx.x >> 4;
#pragma unroll
    for (int r = 0; r < 4; ++r) {
        const int row = ty * 4 + r;
        const float4 v = *(const float4*)(w1 + (size_t)(d0 + row) * D_FF + c0 + tx * 4);
        tile[row][tx * 4 + 0] = v.x;
        tile[row][tx * 4 + 1] = v.y;
        tile[row][tx * 4 + 2] = v.z;
        tile[row][tx * 4 + 3] = v.w;
    }
    __syncthreads();
#pragma unroll
    for (int r = 0; r < 4; ++r) {
        const int c = ty * 4 + r;
        ushort4 o;
        o.x = f2h(tile[tx * 4 + 0][c]);
        o.y = f2h(tile[tx * 4 + 1][c]);
        o.z = f2h(tile[tx * 4 + 2][c]);
        o.w = f2h(tile[tx * 4 + 3][c]);
        *(ushort4*)(w1h + (size_t)(c0 + c) * D_MODEL + d0 + tx * 4) = o;
    }
}

// ---------------------------------------------------------------------------
// Prep B: cast w2 (8.4M f32) -> f16
// ---------------------------------------------------------------------------
__global__ __launch_bounds__(256) void cast_w2(const float* __restrict__ w2,
                                               u16* __restrict__ w2h) {
    const size_t i = ((size_t)blockIdx.x * 256 + threadIdx.x) * 8;
    const float4 a = *(const float4*)(w2 + i);
    const float4 b = *(const float4*)(w2 + i + 4);
    ushort4 oa, ob;
    oa.x = f2h(a.x); oa.y = f2h(a.y); oa.z = f2h(a.z); oa.w = f2h(a.w);
    ob.x = f2h(b.x); ob.y = f2h(b.y); ob.z = f2h(b.z); ob.w = f2h(b.w);
    *(ushort4*)(w2h + i)     = oa;
    *(ushort4*)(w2h + i + 4) = ob;
}

// ---------------------------------------------------------------------------
// Main: j-tiled XCD-affine (jt = blockIdx % 8; round-4 verified L2-resident,
// FETCH 51 MB). f16 weights -> v_fma_mix (no unpack). Phase 1: lane owns a
// 16-elem d-slice, 16 independent j-accumulators, ONE wave-local LDS
// transpose-reduce per rep (replaces round-5's 6-deep shuffle tail per j).
// Partials streamed f16 to ws; reduced by reduce_partials.
// ---------------------------------------------------------------------------
__global__ __launch_bounds__(256) void sparse_ff_jt(const int* __restrict__ mask,
                                                    const float* __restrict__ x,
                                                    const u16* __restrict__ w1h_,
                                                    const u16* __restrict__ w2h_,
                                                    u16* __restrict__ part) {
    const _Float16* w1h = (const _Float16*)w1h_;
    const _Float16* w2h = (const _Float16*)w2h_;
    __shared__ float red[4][16 * 68];   // per-wave 16j x 64 partials, row pad 68
    __shared__ float r_lds[B_T][JT];
    __shared__ int   m_lds[B_T][JT];

    const int jt = blockIdx.x & (NJT - 1);          // XCD-affine j tile
    const int b0 = (blockIdx.x >> 3) * B_T;
    const int t = threadIdx.x;
    const int wave = t >> 6;
    const int lane = t & 63;

    if (t < B_T * JT) {
        m_lds[t >> 4][t & 15] = mask[(b0 + (t >> 4)) * D1 + jt * JT + (t & 15)];
    }
    __syncthreads();

    // ---------------- phase 1: wave handles rows bi = wave*2, wave*2+1 ------
#pragma unroll
    for (int rep = 0; rep < 2; ++rep) {
        const int bi = wave * 2 + rep;
        const float* xrow = x + (size_t)(b0 + bi) * D_MODEL + lane * 16;
        float xr[16];
        *(f32x4*)&xr[0]  = ntload4(xrow);
        *(f32x4*)&xr[4]  = ntload4(xrow + 4);
        *(f32x4*)&xr[8]  = ntload4(xrow + 8);
        *(f32x4*)&xr[12] = ntload4(xrow + 12);

        int mreg[16];
#pragma unroll
        for (int i = 0; i < 16; i += 4) {
            const int4 mv = *(const int4*)&m_lds[bi][i];
            mreg[i] = mv.x; mreg[i + 1] = mv.y; mreg[i + 2] = mv.z; mreg[i + 3] = mv.w;
        }

        float s[16];
#pragma unroll
        for (int j = 0; j < 16; ++j) {
            const _Float16* col = w1h
                + (size_t)(((jt * JT + j) << 6) + mreg[j]) * D_MODEL + lane * 16;
            const uint4 A = *(const uint4*)col;
            const uint4 B = *(const uint4*)(col + 8);
            const u32 w[8] = {A.x, A.y, A.z, A.w, B.x, B.y, B.z, B.w};
            float a = 0.f;
#pragma unroll
            for (int k = 0; k < 8; ++k) {
                const h2 p = as_h2(w[k]);
                a = fmaf((float)p.x, xr[2 * k], a);      // -> v_fma_mix_f32
                a = fmaf((float)p.y, xr[2 * k + 1], a);
            }
            s[j] = a;
        }

        // wave-local transpose-reduce (single wave: LDS ops are in-order)
#pragma unroll
        for (int j = 0; j < 16; ++j) red[wave][j * 68 + lane] = s[j];
        const int q = lane >> 4, jr = lane & 15;
        const float* rb = &red[wave][jr * 68 + q * 16];
        const f32x4 r0 = *(const f32x4*)rb;
        const f32x4 r1 = *(const f32x4*)(rb + 4);
        const f32x4 r2 = *(const f32x4*)(rb + 8);
        const f32x4 r3 = *(const f32x4*)(rb + 12);
        const f32x4 rs = (r0 + r1) + (r2 + r3);
        float v = (rs.x + rs.y) + (rs.z + rs.w);
        v += __shfl_xor(v, 16, 64);
        v += __shfl_xor(v, 32, 64);
        if (lane < 16) r_lds[bi][lane] = fmaxf(v, 0.f);
    }
    __syncthreads();

    // ---------------- phase 2: thread owns 4 output dims --------------------
    const int d0q = t * 4;
    for (int bi = 0; bi < B_T; ++bi) {
        float rr[16];
        *(f32x4*)&rr[0]  = *(const f32x4*)&r_lds[bi][0];
        *(f32x4*)&rr[4]  = *(const f32x4*)&r_lds[bi][4];
        *(f32x4*)&rr[8]  = *(const f32x4*)&r_lds[bi][8];
        *(f32x4*)&rr[12] = *(const f32x4*)&r_lds[bi][12];
        int mr[16];
#pragma unroll
        for (int i = 0; i < 16; i += 4) {
            const int4 mv = *(const int4*)&m_lds[bi][i];
            mr[i] = mv.x; mr[i + 1] = mv.y; mr[i + 2] = mv.z; mr[i + 3] = mv.w;
        }
        float a0 = 0.f, a1 = 0.f, a2 = 0.f, a3 = 0.f;
#pragma unroll
        for (int jj = 0; jj < 16; ++jj) {
            const float r = rr[jj];
            if (r > 0.f) {                       // workgroup-uniform branch
                const _Float16* row = w2h
                    + (size_t)(mr[jj] * D1 + jt * JT + jj) * D_MODEL + d0q;
                const uint2 v = *(const uint2*)row;
                const h2 p0 = as_h2(v.x), p1 = as_h2(v.y);
                a0 = fmaf(r, (float)p0.x, a0); a1 = fmaf(r, (float)p0.y, a1);
                a2 = fmaf(r, (float)p1.x, a2); a3 = fmaf(r, (float)p1.y, a3);
            }
        }
        u32x2 o;
        o.x = pkh(a0, a1);
        o.y = pkh(a2, a3);
        u16* pp = part + ((size_t)jt * BATCH + (b0 + bi)) * D_MODEL + d0q;
        __builtin_nontemporal_store(o, (u32x2*)pp);
    }
}

// ---------------------------------------------------------------------------
// Reduce: res[b] = b2 + sum_jt part[jt][b] (f16 partials); mask echo chunk 0
// ---------------------------------------------------------------------------
__global__ __launch_bounds__(256) void reduce_partials(const int* __restrict__ mask,
                                                       const float* __restrict__ b2,
                                                       const u16* __restrict__ part,
                                                       float* __restrict__ out) {
    const int b = blockIdx.x;
    const int t = threadIdx.x;
    if (t < D1) out[(size_t)b * D1 + t] = (float)mask[b * D1 + t];

    const int d0 = t * 4;
    const float4 bv = *(const float4*)(b2 + d0);
    float a0 = bv.x, a1 = bv.y, a2 = bv.z, a3 = bv.w;
#pragma unroll
    for (int jt = 0; jt < NJT; ++jt) {
        const uint2 v = *(const uint2*)(part + ((size_t)jt * BATCH + b) * D_MODEL + d0);
        const h2 p0 = as_h2(v.x), p1 = as_h2(v.y);
        a0 += (float)p0.x; a1 += (float)p0.y;
        a2 += (float)p1.x; a3 += (float)p1.y;
    }
    *(float4*)(out + (size_t)BATCH * D1 + (size_t)b * D_MODEL + d0) =
        make_float4(a0, a1, a2, a3);
}

// ---------------------------------------------------------------------------
// Fallback (tiny ws): fp32 path, raw strided w1 gather
// ---------------------------------------------------------------------------
__global__ __launch_bounds__(256) void sparse_ff_f32_raw(const int* __restrict__ mask,
                                                         const float* __restrict__ x,
                                                         const float* __restrict__ w1,
                                                         const float* __restrict__ w2,
                                                         const float* __restrict__ b2,
                                                         float* __restrict__ out) {
    __shared__ float x_lds[D_MODEL];
    __shared__ float relu_lds[D1];
    __shared__ int   m_lds[D1];
    const int b = blockIdx.x, t = threadIdx.x;
    const int wave = t >> 6, lane = t & 63;
    *(float4*)&x_lds[t * 4] = *(const float4*)(x + (size_t)b * D_MODEL + t * 4);
    if (t < D1) {
        const int mv = mask[b * D1 + t];
        m_lds[t] = mv;
        out[(size_t)b * D1 + t] = (float)mv;
    }
    __syncthreads();
    for (int jj = 0; jj < 32; ++jj) {
        const int j = wave * 32 + jj;
        const int m = m_lds[j];
        float acc = 0.f;
#pragma unroll
        for (int c = 0; c < 16; ++c) {
            const int d = c * 64 + lane;
            acc = fmaf(w1[(size_t)d * D_FF + j * N_ELEM + m], x_lds[d], acc);
        }
#pragma unroll
        for (int off = 32; off; off >>= 1) acc += __shfl_down(acc, off);
        if (lane == 0) relu_lds[j] = fmaxf(acc, 0.f);
    }
    __syncthreads();
    const int dm0 = t * 4;
    const float4 bv = *(const float4*)(b2 + dm0);
    float a0 = bv.x, a1 = bv.y, a2 = bv.z, a3 = bv.w;
    for (int j = 0; j < D1; ++j) {
        const float r = relu_lds[j];
        if (r > 0.f) {
            const float4 wv = *(const float4*)(w2 + (size_t)(m_lds[j] * D1 + j) * D_MODEL + dm0);
            a0 = fmaf(r, wv.x, a0); a1 = fmaf(r, wv.y, a1);
            a2 = fmaf(r, wv.z, a2); a3 = fmaf(r, wv.w, a3);
        }
    }
    *(float4*)(out + (size_t)BATCH * D1 + (size_t)b * D_MODEL + dm0) =
        make_float4(a0, a1, a2, a3);
}

extern "C" void kernel_launch(void* const* d_in, const int* in_sizes, int n_in,
                              void* d_out, int out_size, void* d_ws, size_t ws_size,
                              hipStream_t stream) {
    const int*   mask = (const int*)d_in[0];
    const float* x    = (const float*)d_in[1];
    const float* w1   = (const float*)d_in[2];
    const float* w2   = (const float*)d_in[3];
    const float* b2   = (const float*)d_in[4];
    float* out = (float*)d_out;

    const size_t w1h_bytes  = (size_t)D_FF * D_MODEL * sizeof(u16);          // 16 MiB
    const size_t w2h_bytes  = (size_t)D_FF * D_MODEL * sizeof(u16);          // 16 MiB
    const size_t part_bytes = (size_t)NJT * BATCH * D_MODEL * sizeof(u16);   // 32 MiB

    if (ws_size >= w1h_bytes + w2h_bytes + part_bytes) {
        u16* w1h  = (u16*)d_ws;
        u16* w2h  = (u16*)((char*)d_ws + w1h_bytes);
        u16* part = (u16*)((char*)d_ws + w1h_bytes + w2h_bytes);
        transpose_cast_w1<<<dim3(D_FF / 64, D_MODEL / 64), 256, 0, stream>>>(w1, w1h);
        cast_w2<<<(D_FF * D_MODEL / 8) / 256, 256, 0, stream>>>(w2, w2h);
        sparse_ff_jt<<<(BATCH / B_T) * NJT, 256, 0, stream>>>(mask, x, w1h, w2h, part);
        reduce_partials<<<BATCH, 256, 0, stream>>>(mask, b2, part, out);
    } else {
        sparse_ff_f32_raw<<<BATCH, 256, 0, stream>>>(mask, x, w1, w2, b2, out);
    }
}

// Round 7
// 208.526 us; speedup vs baseline: 1.0563x; 1.0563x over previous
//
#include <hip/hip_runtime.h>

#define D_MODEL 1024
#define D_FF    8192
#define N_ELEM  64
#define D1      128
#define BATCH   2048
#define B_T     8      // batch rows per block (main kernel)
#define NJT     8      // j tiles (== XCD count)
#define JT      16     // j per tile

typedef unsigned short u16;
typedef unsigned int   u32;
typedef _Float16 h2    __attribute__((ext_vector_type(2)));
typedef float    f32x4 __attribute__((ext_vector_type(4)));
typedef u32      u32x2 __attribute__((ext_vector_type(2)));

__device__ __forceinline__ h2 as_h2(u32 u) { union { u32 i; h2 h; } c; c.i = u; return c.h; }
__device__ __forceinline__ u32 pkh(float a, float b) {
    union { h2 h; u32 u; } c; c.h.x = (_Float16)a; c.h.y = (_Float16)b; return c.u;
}
__device__ __forceinline__ u16 f2h(float f) {
    union { _Float16 h; u16 u; } c; c.h = (_Float16)f; return c.u;
}
__device__ __forceinline__ f32x4 ntload4(const float* p) {
    return __builtin_nontemporal_load((const f32x4*)p);
}

// ---------------------------------------------------------------------------
// Prep A: transpose+cast w1 [d][j*64+e] (1024x8192 f32) -> w1h [j*64+e][d] f16
// ---------------------------------------------------------------------------
__global__ __launch_bounds__(256) void transpose_cast_w1(const float* __restrict__ w1,
                                                         u16* __restrict__ w1h) {
    __shared__ float tile[64][65];
    const int c0 = blockIdx.x * 64;
    const int d0 = blockIdx.y * 64;
    const int tx = threadIdx.x & 15;
    const int ty = threadIdx.x >> 4;
#pragma unroll
    for (int r = 0; r < 4; ++r) {
        const int row = ty * 4 + r;
        const float4 v = *(const float4*)(w1 + (size_t)(d0 + row) * D_FF + c0 + tx * 4);
        tile[row][tx * 4 + 0] = v.x;
        tile[row][tx * 4 + 1] = v.y;
        tile[row][tx * 4 + 2] = v.z;
        tile[row][tx * 4 + 3] = v.w;
    }
    __syncthreads();
#pragma unroll
    for (int r = 0; r < 4; ++r) {
        const int c = ty * 4 + r;
        ushort4 o;
        o.x = f2h(tile[tx * 4 + 0][c]);
        o.y = f2h(tile[tx * 4 + 1][c]);
        o.z = f2h(tile[tx * 4 + 2][c]);
        o.w = f2h(tile[tx * 4 + 3][c]);
        *(ushort4*)(w1h + (size_t)(c0 + c) * D_MODEL + d0 + tx * 4) = o;
    }
}

// ---------------------------------------------------------------------------
// Prep B: cast w2 (8.4M f32) -> f16
// ---------------------------------------------------------------------------
__global__ __launch_bounds__(256) void cast_w2(const float* __restrict__ w2,
                                               u16* __restrict__ w2h) {
    const size_t i = ((size_t)blockIdx.x * 256 + threadIdx.x) * 8;
    const float4 a = *(const float4*)(w2 + i);
    const float4 b = *(const float4*)(w2 + i + 4);
    ushort4 oa, ob;
    oa.x = f2h(a.x); oa.y = f2h(a.y); oa.z = f2h(a.z); oa.w = f2h(a.w);
    ob.x = f2h(b.x); ob.y = f2h(b.y); ob.z = f2h(b.z); ob.w = f2h(b.w);
    *(ushort4*)(w2h + i)     = oa;
    *(ushort4*)(w2h + i + 4) = ob;
}

// ---------------------------------------------------------------------------
// Main: round-5 structure (proven 68 us / FETCH 51 MB) + f16 v_fma_mix MACs +
// 4-j load groups for more MLP. jt = blockIdx % 8 is XCD-affine; 2+2 MB
// weight slices stay L2-resident. Partials streamed f16 to ws.
// ---------------------------------------------------------------------------
__global__ __launch_bounds__(256) void sparse_ff_jt(const int* __restrict__ mask,
                                                    const float* __restrict__ x,
                                                    const u16* __restrict__ w1h_,
                                                    const u16* __restrict__ w2h_,
                                                    u16* __restrict__ part) {
    const _Float16* w1h = (const _Float16*)w1h_;
    const _Float16* w2h = (const _Float16*)w2h_;
    __shared__ float r_lds[B_T][JT];
    __shared__ int   m_lds[B_T][JT];

    const int jt = blockIdx.x & (NJT - 1);          // XCD-affine j tile
    const int b0 = (blockIdx.x >> 3) * B_T;
    const int t = threadIdx.x;
    const int wave = t >> 6;
    const int lane = t & 63;

    if (t < B_T * JT) {
        m_lds[t >> 4][t & 15] = mask[(b0 + (t >> 4)) * D1 + jt * JT + (t & 15)];
    }
    __syncthreads();

    // phase 1: wave handles 2 batch rows x 16 j (4-j load groups)
#pragma unroll
    for (int rep = 0; rep < 2; ++rep) {
        const int bi = wave * 2 + rep;
        const float* xrow = x + (size_t)(b0 + bi) * D_MODEL;
        // x streamed (read once per XCD) -> nontemporal, round-5 proven pattern
        const f32x4 xa0 = ntload4(xrow + lane * 8);
        const f32x4 xa1 = ntload4(xrow + lane * 8 + 4);
        const f32x4 xb0 = ntload4(xrow + 512 + lane * 8);
        const f32x4 xb1 = ntload4(xrow + 512 + lane * 8 + 4);
        float xr[16];
        *(f32x4*)&xr[0]  = xa0; *(f32x4*)&xr[4]  = xa1;
        *(f32x4*)&xr[8]  = xb0; *(f32x4*)&xr[12] = xb1;

        for (int jj = 0; jj < JT; jj += 4) {
            const int j0 = jt * JT + jj;
            uint4 wa[4], wb[4];
#pragma unroll
            for (int q = 0; q < 4; ++q) {
                const _Float16* col = w1h
                    + (size_t)(((j0 + q) << 6) + m_lds[bi][jj + q]) * D_MODEL;
                wa[q] = *(const uint4*)(col + lane * 8);         // 16B/lane, 1KB/inst
                wb[q] = *(const uint4*)(col + 512 + lane * 8);
            }
            float s[4];
#pragma unroll
            for (int q = 0; q < 4; ++q) {
                const u32 w[8] = {wa[q].x, wa[q].y, wa[q].z, wa[q].w,
                                  wb[q].x, wb[q].y, wb[q].z, wb[q].w};
                float a = 0.f;
#pragma unroll
                for (int k = 0; k < 8; ++k) {
                    const h2 p = as_h2(w[k]);
                    a = fmaf((float)p.x, xr[2 * k], a);      // -> v_fma_mix_f32
                    a = fmaf((float)p.y, xr[2 * k + 1], a);
                }
                s[q] = a;
            }
#pragma unroll
            for (int off = 32; off; off >>= 1) {
                s[0] += __shfl_down(s[0], off);
                s[1] += __shfl_down(s[1], off);
                s[2] += __shfl_down(s[2], off);
                s[3] += __shfl_down(s[3], off);
            }
            if (lane == 0) {
                r_lds[bi][jj]     = fmaxf(s[0], 0.f);
                r_lds[bi][jj + 1] = fmaxf(s[1], 0.f);
                r_lds[bi][jj + 2] = fmaxf(s[2], 0.f);
                r_lds[bi][jj + 3] = fmaxf(s[3], 0.f);
            }
        }
    }
    __syncthreads();

    // phase 2: thread owns 4 output dims; f16 w2 rows, fma_mix accumulate
    const int d0q = t * 4;
    for (int bi = 0; bi < B_T; ++bi) {
        float a0 = 0.f, a1 = 0.f, a2 = 0.f, a3 = 0.f;
        for (int jj = 0; jj < JT; ++jj) {
            const float r = r_lds[bi][jj];
            if (r > 0.f) {                       // workgroup-uniform branch
                const _Float16* row = w2h
                    + (size_t)(m_lds[bi][jj] * D1 + jt * JT + jj) * D_MODEL + d0q;
                const uint2 v = *(const uint2*)row;
                const h2 p0 = as_h2(v.x), p1 = as_h2(v.y);
                a0 = fmaf(r, (float)p0.x, a0); a1 = fmaf(r, (float)p0.y, a1);
                a2 = fmaf(r, (float)p1.x, a2); a3 = fmaf(r, (float)p1.y, a3);
            }
        }
        u32x2 o;
        o.x = pkh(a0, a1);
        o.y = pkh(a2, a3);
        u16* pp = part + ((size_t)jt * BATCH + (b0 + bi)) * D_MODEL + d0q;
        __builtin_nontemporal_store(o, (u32x2*)pp);
    }
}

// ---------------------------------------------------------------------------
// Reduce: res[b] = b2 + sum_jt part[jt][b] (f16 partials); mask echo chunk 0
// ---------------------------------------------------------------------------
__global__ __launch_bounds__(256) void reduce_partials(const int* __restrict__ mask,
                                                       const float* __restrict__ b2,
                                                       const u16* __restrict__ part,
                                                       float* __restrict__ out) {
    const int b = blockIdx.x;
    const int t = threadIdx.x;
    if (t < D1) out[(size_t)b * D1 + t] = (float)mask[b * D1 + t];

    const int d0 = t * 4;
    const float4 bv = *(const float4*)(b2 + d0);
    float a0 = bv.x, a1 = bv.y, a2 = bv.z, a3 = bv.w;
#pragma unroll
    for (int jt = 0; jt < NJT; ++jt) {
        const uint2 v = *(const uint2*)(part + ((size_t)jt * BATCH + b) * D_MODEL + d0);
        const h2 p0 = as_h2(v.x), p1 = as_h2(v.y);
        a0 += (float)p0.x; a1 += (float)p0.y;
        a2 += (float)p1.x; a3 += (float)p1.y;
    }
    *(float4*)(out + (size_t)BATCH * D1 + (size_t)b * D_MODEL + d0) =
        make_float4(a0, a1, a2, a3);
}

// ---------------------------------------------------------------------------
// Fallback (tiny ws): fp32 path, raw strided w1 gather
// ---------------------------------------------------------------------------
__global__ __launch_bounds__(256) void sparse_ff_f32_raw(const int* __restrict__ mask,
                                                         const float* __restrict__ x,
                                                         const float* __restrict__ w1,
                                                         const float* __restrict__ w2,
                                                         const float* __restrict__ b2,
                                                         float* __restrict__ out) {
    __shared__ float x_lds[D_MODEL];
    __shared__ float relu_lds[D1];
    __shared__ int   m_lds[D1];
    const int b = blockIdx.x, t = threadIdx.x;
    const int wave = t >> 6, lane = t & 63;
    *(float4*)&x_lds[t * 4] = *(const float4*)(x + (size_t)b * D_MODEL + t * 4);
    if (t < D1) {
        const int mv = mask[b * D1 + t];
        m_lds[t] = mv;
        out[(size_t)b * D1 + t] = (float)mv;
    }
    __syncthreads();
    for (int jj = 0; jj < 32; ++jj) {
        const int j = wave * 32 + jj;
        const int m = m_lds[j];
        float acc = 0.f;
#pragma unroll
        for (int c = 0; c < 16; ++c) {
            const int d = c * 64 + lane;
            acc = fmaf(w1[(size_t)d * D_FF + j * N_ELEM + m], x_lds[d], acc);
        }
#pragma unroll
        for (int off = 32; off; off >>= 1) acc += __shfl_down(acc, off);
        if (lane == 0) relu_lds[j] = fmaxf(acc, 0.f);
    }
    __syncthreads();
    const int dm0 = t * 4;
    const float4 bv = *(const float4*)(b2 + dm0);
    float a0 = bv.x, a1 = bv.y, a2 = bv.z, a3 = bv.w;
    for (int j = 0; j < D1; ++j) {
        const float r = relu_lds[j];
        if (r > 0.f) {
            const float4 wv = *(const float4*)(w2 + (size_t)(m_lds[j] * D1 + j) * D_MODEL + dm0);
            a0 = fmaf(r, wv.x, a0); a1 = fmaf(r, wv.y, a1);
            a2 = fmaf(r, wv.z, a2); a3 = fmaf(r, wv.w, a3);
        }
    }
    *(float4*)(out + (size_t)BATCH * D1 + (size_t)b * D_MODEL + dm0) =
        make_float4(a0, a1, a2, a3);
}

extern "C" void kernel_launch(void* const* d_in, const int* in_sizes, int n_in,
                              void* d_out, int out_size, void* d_ws, size_t ws_size,
                              hipStream_t stream) {
    const int*   mask = (const int*)d_in[0];
    const float* x    = (const float*)d_in[1];
    const float* w1   = (const float*)d_in[2];
    const float* w2   = (const float*)d_in[3];
    const float* b2   = (const float*)d_in[4];
    float* out = (float*)d_out;

    const size_t w1h_bytes  = (size_t)D_FF * D_MODEL * sizeof(u16);          // 16 MiB
    const size_t w2h_bytes  = (size_t)D_FF * D_MODEL * sizeof(u16);          // 16 MiB
    const size_t part_bytes = (size_t)NJT * BATCH * D_MODEL * sizeof(u16);   // 32 MiB

    if (ws_size >= w1h_bytes + w2h_bytes + part_bytes) {
        u16* w1h  = (u16*)d_ws;
        u16* w2h  = (u16*)((char*)d_ws + w1h_bytes);
        u16* part = (u16*)((char*)d_ws + w1h_bytes + w2h_bytes);
        transpose_cast_w1<<<dim3(D_FF / 64, D_MODEL / 64), 256, 0, stream>>>(w1, w1h);
        cast_w2<<<(D_FF * D_MODEL / 8) / 256, 256, 0, stream>>>(w2, w2h);
        sparse_ff_jt<<<(BATCH / B_T) * NJT, 256, 0, stream>>>(mask, x, w1h, w2h, part);
        reduce_partials<<<BATCH, 256, 0, stream>>>(mask, b2, part, out);
    } else {
        sparse_ff_f32_raw<<<BATCH, 256, 0, stream>>>(mask, x, w1, w2, b2, out);
    }
}

// Round 8
// 199.614 us; speedup vs baseline: 1.1035x; 1.0446x over previous
//
#include <hip/hip_runtime.h>

#define D_MODEL 1024
#define D_FF    8192
#define N_ELEM  64
#define D1      128
#define BATCH   2048
#define B_T     8      // batch rows per block (main kernel)
#define NJT     8      // j tiles (== XCD count)
#define JT      16     // j per tile
#define RSTRIDE 65     // red row stride: write banks (j+lane)%32 distinct; read 2-way

typedef unsigned short u16;
typedef unsigned int   u32;
typedef _Float16 h2    __attribute__((ext_vector_type(2)));
typedef float    f32x4 __attribute__((ext_vector_type(4)));
typedef u32      u32x2 __attribute__((ext_vector_type(2)));

__device__ __forceinline__ h2 as_h2(u32 u) { union { u32 i; h2 h; } c; c.i = u; return c.h; }
__device__ __forceinline__ u32 pkh(float a, float b) {
    union { h2 h; u32 u; } c; c.h.x = (_Float16)a; c.h.y = (_Float16)b; return c.u;
}
__device__ __forceinline__ u16 f2h(float f) {
    union { _Float16 h; u16 u; } c; c.h = (_Float16)f; return c.u;
}
__device__ __forceinline__ f32x4 ntload4(const float* p) {
    return __builtin_nontemporal_load((const f32x4*)p);
}

// ---------------------------------------------------------------------------
// Prep A: transpose+cast w1 [d][j*64+e] (1024x8192 f32) -> w1h [j*64+e][d] f16
// ---------------------------------------------------------------------------
__global__ __launch_bounds__(256) void transpose_cast_w1(const float* __restrict__ w1,
                                                         u16* __restrict__ w1h) {
    __shared__ float tile[64][65];
    const int c0 = blockIdx.x * 64;
    const int d0 = blockIdx.y * 64;
    const int tx = threadIdx.x & 15;
    const int ty = threadIdx.x >> 4;
#pragma unroll
    for (int r = 0; r < 4; ++r) {
        const int row = ty * 4 + r;
        const float4 v = *(const float4*)(w1 + (size_t)(d0 + row) * D_FF + c0 + tx * 4);
        tile[row][tx * 4 + 0] = v.x;
        tile[row][tx * 4 + 1] = v.y;
        tile[row][tx * 4 + 2] = v.z;
        tile[row][tx * 4 + 3] = v.w;
    }
    __syncthreads();
#pragma unroll
    for (int r = 0; r < 4; ++r) {
        const int c = ty * 4 + r;
        ushort4 o;
        o.x = f2h(tile[tx * 4 + 0][c]);
        o.y = f2h(tile[tx * 4 + 1][c]);
        o.z = f2h(tile[tx * 4 + 2][c]);
        o.w = f2h(tile[tx * 4 + 3][c]);
        *(ushort4*)(w1h + (size_t)(c0 + c) * D_MODEL + d0 + tx * 4) = o;
    }
}

// ---------------------------------------------------------------------------
// Prep B: cast w2 (8.4M f32) -> f16
// ---------------------------------------------------------------------------
__global__ __launch_bounds__(256) void cast_w2(const float* __restrict__ w2,
                                               u16* __restrict__ w2h) {
    const size_t i = ((size_t)blockIdx.x * 256 + threadIdx.x) * 8;
    const float4 a = *(const float4*)(w2 + i);
    const float4 b = *(const float4*)(w2 + i + 4);
    ushort4 oa, ob;
    oa.x = f2h(a.x); oa.y = f2h(a.y); oa.z = f2h(a.z); oa.w = f2h(a.w);
    ob.x = f2h(b.x); ob.y = f2h(b.y); ob.z = f2h(b.z); ob.w = f2h(b.w);
    *(ushort4*)(w2h + i)     = oa;
    *(ushort4*)(w2h + i + 4) = ob;
}

// ---------------------------------------------------------------------------
// Main: j-tiled XCD-affine (jt = blockIdx % 8; 2+2 MB slices L2-resident,
// round-4 verified). launch_bounds(256,4) -> ~128 VGPRs so the 4-column load
// groups actually stay in flight (round-6/7 failure was silent serialization
// at <=64 VGPR). 16 persistent j-accumulators; ONE LDS transpose-reduce per
// rep (34 ds-ops vs round-5's ~96 ds_bpermute). f16 weights -> v_fma_mix.
// ---------------------------------------------------------------------------
__global__ __launch_bounds__(256, 4) void sparse_ff_jt(const int* __restrict__ mask,
                                                       const float* __restrict__ x,
                                                       const u16* __restrict__ w1h_,
                                                       const u16* __restrict__ w2h_,
                                                       u16* __restrict__ part) {
    const _Float16* w1h = (const _Float16*)w1h_;
    const _Float16* w2h = (const _Float16*)w2h_;
    __shared__ float red[4][JT * RSTRIDE];   // per-wave transpose pad
    __shared__ float r_lds[B_T][JT];
    __shared__ int   m_lds[B_T][JT];

    const int jt = blockIdx.x & (NJT - 1);          // XCD-affine j tile
    const int b0 = (blockIdx.x >> 3) * B_T;
    const int t = threadIdx.x;
    const int wave = t >> 6;
    const int lane = t & 63;

    if (t < B_T * JT) {
        m_lds[t >> 4][t & 15] = mask[(b0 + (t >> 4)) * D1 + jt * JT + (t & 15)];
    }
    __syncthreads();

    // ---------------- phase 1: wave handles rows bi = wave*2, wave*2+1 ------
#pragma unroll
    for (int rep = 0; rep < 2; ++rep) {
        const int bi = wave * 2 + rep;
        const float* xrow = x + (size_t)(b0 + bi) * D_MODEL;
        // round-5-proven x pattern (nt: stream, keep L2 for weights)
        const f32x4 xa0 = ntload4(xrow + lane * 8);
        const f32x4 xa1 = ntload4(xrow + lane * 8 + 4);
        const f32x4 xb0 = ntload4(xrow + 512 + lane * 8);
        const f32x4 xb1 = ntload4(xrow + 512 + lane * 8 + 4);
        float xr[16];
        *(f32x4*)&xr[0]  = xa0; *(f32x4*)&xr[4]  = xa1;
        *(f32x4*)&xr[8]  = xb0; *(f32x4*)&xr[12] = xb1;

        float s[16];
#pragma unroll
        for (int i = 0; i < 16; ++i) s[i] = 0.f;

#pragma unroll
        for (int jj = 0; jj < JT; jj += 4) {
            uint4 wa[4], wb[4];
#pragma unroll
            for (int q = 0; q < 4; ++q) {
                const _Float16* col = w1h
                    + (size_t)(((jt * JT + jj + q) << 6) + m_lds[bi][jj + q]) * D_MODEL;
                wa[q] = *(const uint4*)(col + lane * 8);         // 16B/lane
                wb[q] = *(const uint4*)(col + 512 + lane * 8);
            }
#pragma unroll
            for (int q = 0; q < 4; ++q) {
                const u32 w[8] = {wa[q].x, wa[q].y, wa[q].z, wa[q].w,
                                  wb[q].x, wb[q].y, wb[q].z, wb[q].w};
                float a = s[jj + q];
#pragma unroll
                for (int k = 0; k < 8; ++k) {
                    const h2 p = as_h2(w[k]);
                    a = fmaf((float)p.x, xr[2 * k], a);      // -> v_fma_mix_f32
                    a = fmaf((float)p.y, xr[2 * k + 1], a);
                }
                s[jj + q] = a;
            }
        }

        // wave-local transpose-reduce (single wave: LDS ops in-order)
#pragma unroll
        for (int j = 0; j < 16; ++j) red[wave][j * RSTRIDE + lane] = s[j];
        const int q = lane >> 4, jr = lane & 15;
        const float* rb = &red[wave][jr * RSTRIDE + q * 16];
        float v = 0.f;
#pragma unroll
        for (int i = 0; i < 16; ++i) v += rb[i];     // 2-way bank alias: free
        v += __shfl_xor(v, 16, 64);
        v += __shfl_xor(v, 32, 64);
        if (lane < 16) r_lds[bi][lane] = fmaxf(v, 0.f);
    }
    __syncthreads();

    // ---------------- phase 2: thread owns 4 output dims --------------------
    const int d0q = t * 4;
    for (int bi = 0; bi < B_T; ++bi) {
        float rr[16];
        *(f32x4*)&rr[0]  = *(const f32x4*)&r_lds[bi][0];    // broadcast reads
        *(f32x4*)&rr[4]  = *(const f32x4*)&r_lds[bi][4];
        *(f32x4*)&rr[8]  = *(const f32x4*)&r_lds[bi][8];
        *(f32x4*)&rr[12] = *(const f32x4*)&r_lds[bi][12];
        int mr[16];
#pragma unroll
        for (int i = 0; i < 16; i += 4) {
            const int4 mv = *(const int4*)&m_lds[bi][i];
            mr[i] = mv.x; mr[i + 1] = mv.y; mr[i + 2] = mv.z; mr[i + 3] = mv.w;
        }
        float a0 = 0.f, a1 = 0.f, a2 = 0.f, a3 = 0.f;
#pragma unroll
        for (int jj = 0; jj < 16; ++jj) {
            const float r = rr[jj];
            if (r > 0.f) {                       // workgroup-uniform branch
                const _Float16* row = w2h
                    + (size_t)(mr[jj] * D1 + jt * JT + jj) * D_MODEL + d0q;
                const uint2 v = *(const uint2*)row;
                const h2 p0 = as_h2(v.x), p1 = as_h2(v.y);
                a0 = fmaf(r, (float)p0.x, a0); a1 = fmaf(r, (float)p0.y, a1);
                a2 = fmaf(r, (float)p1.x, a2); a3 = fmaf(r, (float)p1.y, a3);
            }
        }
        u32x2 o;
        o.x = pkh(a0, a1);
        o.y = pkh(a2, a3);
        u16* pp = part + ((size_t)jt * BATCH + (b0 + bi)) * D_MODEL + d0q;
        __builtin_nontemporal_store(o, (u32x2*)pp);
    }
}

// ---------------------------------------------------------------------------
// Reduce: res[b] = b2 + sum_jt part[jt][b] (f16 partials); mask echo chunk 0
// ---------------------------------------------------------------------------
__global__ __launch_bounds__(256) void reduce_partials(const int* __restrict__ mask,
                                                       const float* __restrict__ b2,
                                                       const u16* __restrict__ part,
                                                       float* __restrict__ out) {
    const int b = blockIdx.x;
    const int t = threadIdx.x;
    if (t < D1) out[(size_t)b * D1 + t] = (float)mask[b * D1 + t];

    const int d0 = t * 4;
    const float4 bv = *(const float4*)(b2 + d0);
    float a0 = bv.x, a1 = bv.y, a2 = bv.z, a3 = bv.w;
#pragma unroll
    for (int jt = 0; jt < NJT; ++jt) {
        const uint2 v = *(const uint2*)(part + ((size_t)jt * BATCH + b) * D_MODEL + d0);
        const h2 p0 = as_h2(v.x), p1 = as_h2(v.y);
        a0 += (float)p0.x; a1 += (float)p0.y;
        a2 += (float)p1.x; a3 += (float)p1.y;
    }
    *(float4*)(out + (size_t)BATCH * D1 + (size_t)b * D_MODEL + d0) =
        make_float4(a0, a1, a2, a3);
}

// ---------------------------------------------------------------------------
// Fallback (tiny ws): fp32 path, raw strided w1 gather
// ---------------------------------------------------------------------------
__global__ __launch_bounds__(256) void sparse_ff_f32_raw(const int* __restrict__ mask,
                                                         const float* __restrict__ x,
                                                         const float* __restrict__ w1,
                                                         const float* __restrict__ w2,
                                                         const float* __restrict__ b2,
                                                         float* __restrict__ out) {
    __shared__ float x_lds[D_MODEL];
    __shared__ float relu_lds[D1];
    __shared__ int   m_lds[D1];
    const int b = blockIdx.x, t = threadIdx.x;
    const int wave = t >> 6, lane = t & 63;
    *(float4*)&x_lds[t * 4] = *(const float4*)(x + (size_t)b * D_MODEL + t * 4);
    if (t < D1) {
        const int mv = mask[b * D1 + t];
        m_lds[t] = mv;
        out[(size_t)b * D1 + t] = (float)mv;
    }
    __syncthreads();
    for (int jj = 0; jj < 32; ++jj) {
        const int j = wave * 32 + jj;
        const int m = m_lds[j];
        float acc = 0.f;
#pragma unroll
        for (int c = 0; c < 16; ++c) {
            const int d = c * 64 + lane;
            acc = fmaf(w1[(size_t)d * D_FF + j * N_ELEM + m], x_lds[d], acc);
        }
#pragma unroll
        for (int off = 32; off; off >>= 1) acc += __shfl_down(acc, off);
        if (lane == 0) relu_lds[j] = fmaxf(acc, 0.f);
    }
    __syncthreads();
    const int dm0 = t * 4;
    const float4 bv = *(const float4*)(b2 + dm0);
    float a0 = bv.x, a1 = bv.y, a2 = bv.z, a3 = bv.w;
    for (int j = 0; j < D1; ++j) {
        const float r = relu_lds[j];
        if (r > 0.f) {
            const float4 wv = *(const float4*)(w2 + (size_t)(m_lds[j] * D1 + j) * D_MODEL + dm0);
            a0 = fmaf(r, wv.x, a0); a1 = fmaf(r, wv.y, a1);
            a2 = fmaf(r, wv.z, a2); a3 = fmaf(r, wv.w, a3);
        }
    }
    *(float4*)(out + (size_t)BATCH * D1 + (size_t)b * D_MODEL + dm0) =
        make_float4(a0, a1, a2, a3);
}

extern "C" void kernel_launch(void* const* d_in, const int* in_sizes, int n_in,
                              void* d_out, int out_size, void* d_ws, size_t ws_size,
                              hipStream_t stream) {
    const int*   mask = (const int*)d_in[0];
    const float* x    = (const float*)d_in[1];
    const float* w1   = (const float*)d_in[2];
    const float* w2   = (const float*)d_in[3];
    const float* b2   = (const float*)d_in[4];
    float* out = (float*)d_out;

    const size_t w1h_bytes  = (size_t)D_FF * D_MODEL * sizeof(u16);          // 16 MiB
    const size_t w2h_bytes  = (size_t)D_FF * D_MODEL * sizeof(u16);          // 16 MiB
    const size_t part_bytes = (size_t)NJT * BATCH * D_MODEL * sizeof(u16);   // 32 MiB

    if (ws_size >= w1h_bytes + w2h_bytes + part_bytes) {
        u16* w1h  = (u16*)d_ws;
        u16* w2h  = (u16*)((char*)d_ws + w1h_bytes);
        u16* part = (u16*)((char*)d_ws + w1h_bytes + w2h_bytes);
        transpose_cast_w1<<<dim3(D_FF / 64, D_MODEL / 64), 256, 0, stream>>>(w1, w1h);
        cast_w2<<<(D_FF * D_MODEL / 8) / 256, 256, 0, stream>>>(w2, w2h);
        sparse_ff_jt<<<(BATCH / B_T) * NJT, 256, 0, stream>>>(mask, x, w1h, w2h, part);
        reduce_partials<<<BATCH, 256, 0, stream>>>(mask, b2, part, out);
    } else {
        sparse_ff_f32_raw<<<BATCH, 256, 0, stream>>>(mask, x, w1, w2, b2, out);
    }
}

// Round 9
// 189.574 us; speedup vs baseline: 1.1620x; 1.0530x over previous
//
#include <hip/hip_runtime.h>

#define D_MODEL 1024
#define D_FF    8192
#define N_ELEM  64
#define D1      128
#define BATCH   2048
#define B_T     8      // batch rows per block (main kernel)
#define NJT     8      // j tiles (== XCD count)
#define JT      16     // j per tile

typedef unsigned short u16;
typedef unsigned int   u32;
typedef _Float16 h2    __attribute__((ext_vector_type(2)));
typedef float    f32x4 __attribute__((ext_vector_type(4)));
typedef u32      u32x2 __attribute__((ext_vector_type(2)));

__device__ __forceinline__ h2 as_h2(u32 u) { union { u32 i; h2 h; } c; c.i = u; return c.h; }
__device__ __forceinline__ u32 pkh(float a, float b) {
    union { h2 h; u32 u; } c; c.h.x = (_Float16)a; c.h.y = (_Float16)b; return c.u;
}
__device__ __forceinline__ u16 f2h(float f) {
    union { _Float16 h; u16 u; } c; c.h = (_Float16)f; return c.u;
}
__device__ __forceinline__ f32x4 ntload4(const float* p) {
    return __builtin_nontemporal_load((const f32x4*)p);
}

// ---------------------------------------------------------------------------
// Prep A: transpose+cast w1 [d][j*64+e] (1024x8192 f32) -> w1h [j*64+e][d] f16
// ---------------------------------------------------------------------------
__global__ __launch_bounds__(256) void transpose_cast_w1(const float* __restrict__ w1,
                                                         u16* __restrict__ w1h) {
    __shared__ float tile[64][65];
    const int c0 = blockIdx.x * 64;
    const int d0 = blockIdx.y * 64;
    const int tx = threadIdx.x & 15;
    const int ty = threadIdx.x >> 4;
#pragma unroll
    for (int r = 0; r < 4; ++r) {
        const int row = ty * 4 + r;
        const float4 v = *(const float4*)(w1 + (size_t)(d0 + row) * D_FF + c0 + tx * 4);
        tile[row][tx * 4 + 0] = v.x;
        tile[row][tx * 4 + 1] = v.y;
        tile[row][tx * 4 + 2] = v.z;
        tile[row][tx * 4 + 3] = v.w;
    }
    __syncthreads();
#pragma unroll
    for (int r = 0; r < 4; ++r) {
        const int c = ty * 4 + r;
        ushort4 o;
        o.x = f2h(tile[tx * 4 + 0][c]);
        o.y = f2h(tile[tx * 4 + 1][c]);
        o.z = f2h(tile[tx * 4 + 2][c]);
        o.w = f2h(tile[tx * 4 + 3][c]);
        *(ushort4*)(w1h + (size_t)(c0 + c) * D_MODEL + d0 + tx * 4) = o;
    }
}

// ---------------------------------------------------------------------------
// Prep B: cast w2 (8.4M f32) -> f16
// ---------------------------------------------------------------------------
__global__ __launch_bounds__(256) void cast_w2(const float* __restrict__ w2,
                                               u16* __restrict__ w2h) {
    const size_t i = ((size_t)blockIdx.x * 256 + threadIdx.x) * 8;
    const float4 a = *(const float4*)(w2 + i);
    const float4 b = *(const float4*)(w2 + i + 4);
    ushort4 oa, ob;
    oa.x = f2h(a.x); oa.y = f2h(a.y); oa.z = f2h(a.z); oa.w = f2h(a.w);
    ob.x = f2h(b.x); ob.y = f2h(b.y); ob.z = f2h(b.z); ob.w = f2h(b.w);
    *(ushort4*)(w2h + i)     = oa;
    *(ushort4*)(w2h + i + 4) = ob;
}

// ---------------------------------------------------------------------------
// Main: EXACT round-5 skeleton (proven 68 us / FETCH 51 MB / occ 73%) with
// ONLY the weight dtype changed bf16 -> f16 (v_fma_mix: 1 VALU op per MAC
// instead of 2). Rounds 6-8 proved every skeleton restructure (wide groups,
// persistent accumulators, LDS transpose-reduce, launch_bounds) regresses
// via occupancy loss or load serialization — do not touch the skeleton.
// ---------------------------------------------------------------------------
__global__ __launch_bounds__(256) void sparse_ff_jt(const int* __restrict__ mask,
                                                    const float* __restrict__ x,
                                                    const u16* __restrict__ w1h_,
                                                    const u16* __restrict__ w2h_,
                                                    u16* __restrict__ part) {
    const _Float16* w1h = (const _Float16*)w1h_;
    const _Float16* w2h = (const _Float16*)w2h_;
    __shared__ float r_lds[B_T][JT];
    __shared__ int   m_lds[B_T][JT];

    const int jt = blockIdx.x & (NJT - 1);          // XCD-affine j tile
    const int b0 = (blockIdx.x >> 3) * B_T;
    const int t = threadIdx.x;
    const int wave = t >> 6;
    const int lane = t & 63;

    if (t < B_T * JT) {
        m_lds[t >> 4][t & 15] = mask[(b0 + (t >> 4)) * D1 + jt * JT + (t & 15)];
    }
    __syncthreads();

    // phase 1: wave handles 2 batch rows x 16 j (2-j groups, round-5 exact)
#pragma unroll
    for (int rep = 0; rep < 2; ++rep) {
        const int bi = wave * 2 + rep;
        const float* xrow = x + (size_t)(b0 + bi) * D_MODEL;
        // x streamed (read once per XCD) -> nontemporal, keep L2 for weights
        const f32x4 xa0 = ntload4(xrow + lane * 8);
        const f32x4 xa1 = ntload4(xrow + lane * 8 + 4);
        const f32x4 xb0 = ntload4(xrow + 512 + lane * 8);
        const f32x4 xb1 = ntload4(xrow + 512 + lane * 8 + 4);

        for (int jj = 0; jj < JT; jj += 2) {
            const int j0 = jt * JT + jj;
            const _Float16* c0 = w1h + (size_t)((j0 << 6) + m_lds[bi][jj]) * D_MODEL;
            const _Float16* c1 = w1h + (size_t)(((j0 + 1) << 6) + m_lds[bi][jj + 1]) * D_MODEL;
            const uint4 a0 = *(const uint4*)(c0 + lane * 8);
            const uint4 b0v = *(const uint4*)(c0 + 512 + lane * 8);
            const uint4 a1 = *(const uint4*)(c1 + lane * 8);
            const uint4 b1v = *(const uint4*)(c1 + 512 + lane * 8);

            float s0 = 0.f, s1 = 0.f;
            {
                const h2 p0 = as_h2(a0.x), p1 = as_h2(a0.y), p2 = as_h2(a0.z), p3 = as_h2(a0.w);
                s0 = fmaf((float)p0.x, xa0.x, s0); s0 = fmaf((float)p0.y, xa0.y, s0);
                s0 = fmaf((float)p1.x, xa0.z, s0); s0 = fmaf((float)p1.y, xa0.w, s0);
                s0 = fmaf((float)p2.x, xa1.x, s0); s0 = fmaf((float)p2.y, xa1.y, s0);
                s0 = fmaf((float)p3.x, xa1.z, s0); s0 = fmaf((float)p3.y, xa1.w, s0);
            }
            {
                const h2 p0 = as_h2(b0v.x), p1 = as_h2(b0v.y), p2 = as_h2(b0v.z), p3 = as_h2(b0v.w);
                s0 = fmaf((float)p0.x, xb0.x, s0); s0 = fmaf((float)p0.y, xb0.y, s0);
                s0 = fmaf((float)p1.x, xb0.z, s0); s0 = fmaf((float)p1.y, xb0.w, s0);
                s0 = fmaf((float)p2.x, xb1.x, s0); s0 = fmaf((float)p2.y, xb1.y, s0);
                s0 = fmaf((float)p3.x, xb1.z, s0); s0 = fmaf((float)p3.y, xb1.w, s0);
            }
            {
                const h2 p0 = as_h2(a1.x), p1 = as_h2(a1.y), p2 = as_h2(a1.z), p3 = as_h2(a1.w);
                s1 = fmaf((float)p0.x, xa0.x, s1); s1 = fmaf((float)p0.y, xa0.y, s1);
                s1 = fmaf((float)p1.x, xa0.z, s1); s1 = fmaf((float)p1.y, xa0.w, s1);
                s1 = fmaf((float)p2.x, xa1.x, s1); s1 = fmaf((float)p2.y, xa1.y, s1);
                s1 = fmaf((float)p3.x, xa1.z, s1); s1 = fmaf((float)p3.y, xa1.w, s1);
            }
            {
                const h2 p0 = as_h2(b1v.x), p1 = as_h2(b1v.y), p2 = as_h2(b1v.z), p3 = as_h2(b1v.w);
                s1 = fmaf((float)p0.x, xb0.x, s1); s1 = fmaf((float)p0.y, xb0.y, s1);
                s1 = fmaf((float)p1.x, xb0.z, s1); s1 = fmaf((float)p1.y, xb0.w, s1);
                s1 = fmaf((float)p2.x, xb1.x, s1); s1 = fmaf((float)p2.y, xb1.y, s1);
                s1 = fmaf((float)p3.x, xb1.z, s1); s1 = fmaf((float)p3.y, xb1.w, s1);
            }

#pragma unroll
            for (int off = 32; off; off >>= 1) {
                s0 += __shfl_down(s0, off);
                s1 += __shfl_down(s1, off);
            }
            if (lane == 0) {
                r_lds[bi][jj]     = fmaxf(s0, 0.f);
                r_lds[bi][jj + 1] = fmaxf(s1, 0.f);
            }
        }
    }
    __syncthreads();

    // phase 2: thread owns 4 output dims (round-5 exact, f16 loads)
    const int d0q = t * 4;
    for (int bi = 0; bi < B_T; ++bi) {
        float a0 = 0.f, a1 = 0.f, a2 = 0.f, a3 = 0.f;
        for (int jj = 0; jj < JT; ++jj) {
            const float r = r_lds[bi][jj];
            if (r > 0.f) {                           // workgroup-uniform branch
                const _Float16* row = w2h
                    + (size_t)(m_lds[bi][jj] * D1 + jt * JT + jj) * D_MODEL + d0q;
                const uint2 v = *(const uint2*)row;
                const h2 p0 = as_h2(v.x), p1 = as_h2(v.y);
                a0 = fmaf(r, (float)p0.x, a0); a1 = fmaf(r, (float)p0.y, a1);
                a2 = fmaf(r, (float)p1.x, a2); a3 = fmaf(r, (float)p1.y, a3);
            }
        }
        u32x2 o;
        o.x = pkh(a0, a1);
        o.y = pkh(a2, a3);
        u16* pp = part + ((size_t)jt * BATCH + (b0 + bi)) * D_MODEL + d0q;
        __builtin_nontemporal_store(o, (u32x2*)pp);
    }
}

// ---------------------------------------------------------------------------
// Reduce: res[b] = b2 + sum_jt part[jt][b] (f16 partials); mask echo chunk 0
// ---------------------------------------------------------------------------
__global__ __launch_bounds__(256) void reduce_partials(const int* __restrict__ mask,
                                                       const float* __restrict__ b2,
                                                       const u16* __restrict__ part,
                                                       float* __restrict__ out) {
    const int b = blockIdx.x;
    const int t = threadIdx.x;
    if (t < D1) out[(size_t)b * D1 + t] = (float)mask[b * D1 + t];

    const int d0 = t * 4;
    const float4 bv = *(const float4*)(b2 + d0);
    float a0 = bv.x, a1 = bv.y, a2 = bv.z, a3 = bv.w;
#pragma unroll
    for (int jt = 0; jt < NJT; ++jt) {
        const uint2 v = *(const uint2*)(part + ((size_t)jt * BATCH + b) * D_MODEL + d0);
        const h2 p0 = as_h2(v.x), p1 = as_h2(v.y);
        a0 += (float)p0.x; a1 += (float)p0.y;
        a2 += (float)p1.x; a3 += (float)p1.y;
    }
    *(float4*)(out + (size_t)BATCH * D1 + (size_t)b * D_MODEL + d0) =
        make_float4(a0, a1, a2, a3);
}

// ---------------------------------------------------------------------------
// Fallback (tiny ws): fp32 path, raw strided w1 gather
// ---------------------------------------------------------------------------
__global__ __launch_bounds__(256) void sparse_ff_f32_raw(const int* __restrict__ mask,
                                                         const float* __restrict__ x,
                                                         const float* __restrict__ w1,
                                                         const float* __restrict__ w2,
                                                         const float* __restrict__ b2,
                                                         float* __restrict__ out) {
    __shared__ float x_lds[D_MODEL];
    __shared__ float relu_lds[D1];
    __shared__ int   m_lds[D1];
    const int b = blockIdx.x, t = threadIdx.x;
    const int wave = t >> 6, lane = t & 63;
    *(float4*)&x_lds[t * 4] = *(const float4*)(x + (size_t)b * D_MODEL + t * 4);
    if (t < D1) {
        const int mv = mask[b * D1 + t];
        m_lds[t] = mv;
        out[(size_t)b * D1 + t] = (float)mv;
    }
    __syncthreads();
    for (int jj = 0; jj < 32; ++jj) {
        const int j = wave * 32 + jj;
        const int m = m_lds[j];
        float acc = 0.f;
#pragma unroll
        for (int c = 0; c < 16; ++c) {
            const int d = c * 64 + lane;
            acc = fmaf(w1[(size_t)d * D_FF + j * N_ELEM + m], x_lds[d], acc);
        }
#pragma unroll
        for (int off = 32; off; off >>= 1) acc += __shfl_down(acc, off);
        if (lane == 0) relu_lds[j] = fmaxf(acc, 0.f);
    }
    __syncthreads();
    const int dm0 = t * 4;
    const float4 bv = *(const float4*)(b2 + dm0);
    float a0 = bv.x, a1 = bv.y, a2 = bv.z, a3 = bv.w;
    for (int j = 0; j < D1; ++j) {
        const float r = relu_lds[j];
        if (r > 0.f) {
            const float4 wv = *(const float4*)(w2 + (size_t)(m_lds[j] * D1 + j) * D_MODEL + dm0);
            a0 = fmaf(r, wv.x, a0); a1 = fmaf(r, wv.y, a1);
            a2 = fmaf(r, wv.z, a2); a3 = fmaf(r, wv.w, a3);
        }
    }
    *(float4*)(out + (size_t)BATCH * D1 + (size_t)b * D_MODEL + dm0) =
        make_float4(a0, a1, a2, a3);
}

extern "C" void kernel_launch(void* const* d_in, const int* in_sizes, int n_in,
                              void* d_out, int out_size, void* d_ws, size_t ws_size,
                              hipStream_t stream) {
    const int*   mask = (const int*)d_in[0];
    const float* x    = (const float*)d_in[1];
    const float* w1   = (const float*)d_in[2];
    const float* w2   = (const float*)d_in[3];
    const float* b2   = (const float*)d_in[4];
    float* out = (float*)d_out;

    const size_t w1h_bytes  = (size_t)D_FF * D_MODEL * sizeof(u16);          // 16 MiB
    const size_t w2h_bytes  = (size_t)D_FF * D_MODEL * sizeof(u16);          // 16 MiB
    const size_t part_bytes = (size_t)NJT * BATCH * D_MODEL * sizeof(u16);   // 32 MiB

    if (ws_size >= w1h_bytes + w2h_bytes + part_bytes) {
        u16* w1h  = (u16*)d_ws;
        u16* w2h  = (u16*)((char*)d_ws + w1h_bytes);
        u16* part = (u16*)((char*)d_ws + w1h_bytes + w2h_bytes);
        transpose_cast_w1<<<dim3(D_FF / 64, D_MODEL / 64), 256, 0, stream>>>(w1, w1h);
        cast_w2<<<(D_FF * D_MODEL / 8) / 256, 256, 0, stream>>>(w2, w2h);
        sparse_ff_jt<<<(BATCH / B_T) * NJT, 256, 0, stream>>>(mask, x, w1h, w2h, part);
        reduce_partials<<<BATCH, 256, 0, stream>>>(mask, b2, part, out);
    } else {
        sparse_ff_f32_raw<<<BATCH, 256, 0, stream>>>(mask, x, w1, w2, b2, out);
    }
}

// Round 10
// 183.138 us; speedup vs baseline: 1.2028x; 1.0351x over previous
//
#include <hip/hip_runtime.h>

#define D_MODEL 1024
#define D_FF    8192
#define N_ELEM  64
#define D1      128
#define BATCH   2048
#define B_T     8      // batch rows per block (main kernel)
#define NJT     8      // j tiles (== XCD count)
#define JT      16     // j per tile

typedef unsigned short u16;
typedef unsigned int   u32;
typedef _Float16 h2    __attribute__((ext_vector_type(2)));
typedef float    f32x4 __attribute__((ext_vector_type(4)));
typedef u32      u32x2 __attribute__((ext_vector_type(2)));

__device__ __forceinline__ h2 as_h2(u32 u) { union { u32 i; h2 h; } c; c.i = u; return c.h; }
__device__ __forceinline__ u32 pkh(float a, float b) {
    union { h2 h; u32 u; } c; c.h.x = (_Float16)a; c.h.y = (_Float16)b; return c.u;
}
__device__ __forceinline__ u16 f2h(float f) {
    union { _Float16 h; u16 u; } c; c.h = (_Float16)f; return c.u;
}
__device__ __forceinline__ f32x4 ntload4(const float* p) {
    return __builtin_nontemporal_load((const f32x4*)p);
}

// ---------------------------------------------------------------------------
// Prep A: transpose+cast w1 [d][j*64+e] (1024x8192 f32) -> w1h [j*64+e][d] f16
// ---------------------------------------------------------------------------
__global__ __launch_bounds__(256) void transpose_cast_w1(const float* __restrict__ w1,
                                                         u16* __restrict__ w1h) {
    __shared__ float tile[64][65];
    const int c0 = blockIdx.x * 64;
    const int d0 = blockIdx.y * 64;
    const int tx = threadIdx.x & 15;
    const int ty = threadIdx.x >> 4;
#pragma unroll
    for (int r = 0; r < 4; ++r) {
        const int row = ty * 4 + r;
        const float4 v = *(const float4*)(w1 + (size_t)(d0 + row) * D_FF + c0 + tx * 4);
        tile[row][tx * 4 + 0] = v.x;
        tile[row][tx * 4 + 1] = v.y;
        tile[row][tx * 4 + 2] = v.z;
        tile[row][tx * 4 + 3] = v.w;
    }
    __syncthreads();
#pragma unroll
    for (int r = 0; r < 4; ++r) {
        const int c = ty * 4 + r;
        ushort4 o;
        o.x = f2h(tile[tx * 4 + 0][c]);
        o.y = f2h(tile[tx * 4 + 1][c]);
        o.z = f2h(tile[tx * 4 + 2][c]);
        o.w = f2h(tile[tx * 4 + 3][c]);
        *(ushort4*)(w1h + (size_t)(c0 + c) * D_MODEL + d0 + tx * 4) = o;
    }
}

// ---------------------------------------------------------------------------
// Prep B: cast w2 (8.4M f32) -> f16
// ---------------------------------------------------------------------------
__global__ __launch_bounds__(256) void cast_w2(const float* __restrict__ w2,
                                               u16* __restrict__ w2h) {
    const size_t i = ((size_t)blockIdx.x * 256 + threadIdx.x) * 8;
    const float4 a = *(const float4*)(w2 + i);
    const float4 b = *(const float4*)(w2 + i + 4);
    ushort4 oa, ob;
    oa.x = f2h(a.x); oa.y = f2h(a.y); oa.z = f2h(a.z); oa.w = f2h(a.w);
    ob.x = f2h(b.x); ob.y = f2h(b.y); ob.z = f2h(b.z); ob.w = f2h(b.w);
    *(ushort4*)(w2h + i)     = oa;
    *(ushort4*)(w2h + i + 4) = ob;
}

// ---------------------------------------------------------------------------
// Main: round-5/9 skeleton (proven 68 us / FETCH 51 MB / occ ~70%). ONLY
// change vs r9: block's 8 x rows staged ONCE into LDS as f16 (16 KB), phase-1
// x fragments become loop-invariant ds_read_b128 (8 VGPRs). Fixes r9's
// VGPR=24 pathology where the compiler rematerialized 4 global x loads per
// j-group (~450 MB hidden L2 traffic). f16 w + f16 x -> v_fma_mix, fp32 acc.
// ---------------------------------------------------------------------------
__global__ __launch_bounds__(256) void sparse_ff_jt(const int* __restrict__ mask,
                                                    const float* __restrict__ x,
                                                    const u16* __restrict__ w1h_,
                                                    const u16* __restrict__ w2h_,
                                                    u16* __restrict__ part) {
    const _Float16* w1h = (const _Float16*)w1h_;
    const _Float16* w2h = (const _Float16*)w2h_;
    __shared__ u16   x_lds[B_T][D_MODEL];   // f16, 16 KB
    __shared__ float r_lds[B_T][JT];
    __shared__ int   m_lds[B_T][JT];

    const int jt = blockIdx.x & (NJT - 1);          // XCD-affine j tile
    const int b0 = (blockIdx.x >> 3) * B_T;
    const int t = threadIdx.x;
    const int wave = t >> 6;
    const int lane = t & 63;

    // stage x rows (f32 nt coalesced -> f16 LDS) + mask row, one barrier
#pragma unroll
    for (int r = 0; r < B_T; ++r) {
        const f32x4 v = ntload4(x + (size_t)(b0 + r) * D_MODEL + t * 4);
        u32x2 o; o.x = pkh(v.x, v.y); o.y = pkh(v.z, v.w);
        *(u32x2*)&x_lds[r][t * 4] = o;
    }
    if (t < B_T * JT) {
        m_lds[t >> 4][t & 15] = mask[(b0 + (t >> 4)) * D1 + jt * JT + (t & 15)];
    }
    __syncthreads();

    // phase 1: wave handles 2 batch rows x 16 j (2-j groups, r5/r9 skeleton)
#pragma unroll
    for (int rep = 0; rep < 2; ++rep) {
        const int bi = wave * 2 + rep;
        // loop-invariant x fragments from LDS (16B each, conflict-free)
        const uint4 xA = *(const uint4*)&x_lds[bi][lane * 8];        // elems lane*8..+8
        const uint4 xB = *(const uint4*)&x_lds[bi][512 + lane * 8];  // elems 512+lane*8..+8

        for (int jj = 0; jj < JT; jj += 2) {
            const int j0 = jt * JT + jj;
            const _Float16* c0 = w1h + (size_t)((j0 << 6) + m_lds[bi][jj]) * D_MODEL;
            const _Float16* c1 = w1h + (size_t)(((j0 + 1) << 6) + m_lds[bi][jj + 1]) * D_MODEL;
            const uint4 a0 = *(const uint4*)(c0 + lane * 8);
            const uint4 b0v = *(const uint4*)(c0 + 512 + lane * 8);
            const uint4 a1 = *(const uint4*)(c1 + lane * 8);
            const uint4 b1v = *(const uint4*)(c1 + 512 + lane * 8);

            float s0 = 0.f, s1 = 0.f;
            {
                const h2 w_0 = as_h2(a0.x), w_1 = as_h2(a0.y), w_2 = as_h2(a0.z), w_3 = as_h2(a0.w);
                const h2 q_0 = as_h2(xA.x), q_1 = as_h2(xA.y), q_2 = as_h2(xA.z), q_3 = as_h2(xA.w);
                s0 = fmaf((float)w_0.x, (float)q_0.x, s0); s0 = fmaf((float)w_0.y, (float)q_0.y, s0);
                s0 = fmaf((float)w_1.x, (float)q_1.x, s0); s0 = fmaf((float)w_1.y, (float)q_1.y, s0);
                s0 = fmaf((float)w_2.x, (float)q_2.x, s0); s0 = fmaf((float)w_2.y, (float)q_2.y, s0);
                s0 = fmaf((float)w_3.x, (float)q_3.x, s0); s0 = fmaf((float)w_3.y, (float)q_3.y, s0);
            }
            {
                const h2 w_0 = as_h2(b0v.x), w_1 = as_h2(b0v.y), w_2 = as_h2(b0v.z), w_3 = as_h2(b0v.w);
                const h2 q_0 = as_h2(xB.x), q_1 = as_h2(xB.y), q_2 = as_h2(xB.z), q_3 = as_h2(xB.w);
                s0 = fmaf((float)w_0.x, (float)q_0.x, s0); s0 = fmaf((float)w_0.y, (float)q_0.y, s0);
                s0 = fmaf((float)w_1.x, (float)q_1.x, s0); s0 = fmaf((float)w_1.y, (float)q_1.y, s0);
                s0 = fmaf((float)w_2.x, (float)q_2.x, s0); s0 = fmaf((float)w_2.y, (float)q_2.y, s0);
                s0 = fmaf((float)w_3.x, (float)q_3.x, s0); s0 = fmaf((float)w_3.y, (float)q_3.y, s0);
            }
            {
                const h2 w_0 = as_h2(a1.x), w_1 = as_h2(a1.y), w_2 = as_h2(a1.z), w_3 = as_h2(a1.w);
                const h2 q_0 = as_h2(xA.x), q_1 = as_h2(xA.y), q_2 = as_h2(xA.z), q_3 = as_h2(xA.w);
                s1 = fmaf((float)w_0.x, (float)q_0.x, s1); s1 = fmaf((float)w_0.y, (float)q_0.y, s1);
                s1 = fmaf((float)w_1.x, (float)q_1.x, s1); s1 = fmaf((float)w_1.y, (float)q_1.y, s1);
                s1 = fmaf((float)w_2.x, (float)q_2.x, s1); s1 = fmaf((float)w_2.y, (float)q_2.y, s1);
                s1 = fmaf((float)w_3.x, (float)q_3.x, s1); s1 = fmaf((float)w_3.y, (float)q_3.y, s1);
            }
            {
                const h2 w_0 = as_h2(b1v.x), w_1 = as_h2(b1v.y), w_2 = as_h2(b1v.z), w_3 = as_h2(b1v.w);
                const h2 q_0 = as_h2(xB.x), q_1 = as_h2(xB.y), q_2 = as_h2(xB.z), q_3 = as_h2(xB.w);
                s1 = fmaf((float)w_0.x, (float)q_0.x, s1); s1 = fmaf((float)w_0.y, (float)q_0.y, s1);
                s1 = fmaf((float)w_1.x, (float)q_1.x, s1); s1 = fmaf((float)w_1.y, (float)q_1.y, s1);
                s1 = fmaf((float)w_2.x, (float)q_2.x, s1); s1 = fmaf((float)w_2.y, (float)q_2.y, s1);
                s1 = fmaf((float)w_3.x, (float)q_3.x, s1); s1 = fmaf((float)w_3.y, (float)q_3.y, s1);
            }

#pragma unroll
            for (int off = 32; off; off >>= 1) {
                s0 += __shfl_down(s0, off);
                s1 += __shfl_down(s1, off);
            }
            if (lane == 0) {
                r_lds[bi][jj]     = fmaxf(s0, 0.f);
                r_lds[bi][jj + 1] = fmaxf(s1, 0.f);
            }
        }
    }
    __syncthreads();

    // phase 2: thread owns 4 output dims (r9 exact)
    const int d0q = t * 4;
    for (int bi = 0; bi < B_T; ++bi) {
        float a0 = 0.f, a1 = 0.f, a2 = 0.f, a3 = 0.f;
        for (int jj = 0; jj < JT; ++jj) {
            const float r = r_lds[bi][jj];
            if (r > 0.f) {                           // workgroup-uniform branch
                const _Float16* row = w2h
                    + (size_t)(m_lds[bi][jj] * D1 + jt * JT + jj) * D_MODEL + d0q;
                const uint2 v = *(const uint2*)row;
                const h2 p0 = as_h2(v.x), p1 = as_h2(v.y);
                a0 = fmaf(r, (float)p0.x, a0); a1 = fmaf(r, (float)p0.y, a1);
                a2 = fmaf(r, (float)p1.x, a2); a3 = fmaf(r, (float)p1.y, a3);
            }
        }
        u32x2 o;
        o.x = pkh(a0, a1);
        o.y = pkh(a2, a3);
        u16* pp = part + ((size_t)jt * BATCH + (b0 + bi)) * D_MODEL + d0q;
        __builtin_nontemporal_store(o, (u32x2*)pp);
    }
}

// ---------------------------------------------------------------------------
// Reduce: res[b] = b2 + sum_jt part[jt][b] (f16 partials); mask echo chunk 0
// ---------------------------------------------------------------------------
__global__ __launch_bounds__(256) void reduce_partials(const int* __restrict__ mask,
                                                       const float* __restrict__ b2,
                                                       const u16* __restrict__ part,
                                                       float* __restrict__ out) {
    const int b = blockIdx.x;
    const int t = threadIdx.x;
    if (t < D1) out[(size_t)b * D1 + t] = (float)mask[b * D1 + t];

    const int d0 = t * 4;
    const float4 bv = *(const float4*)(b2 + d0);
    float a0 = bv.x, a1 = bv.y, a2 = bv.z, a3 = bv.w;
#pragma unroll
    for (int jt = 0; jt < NJT; ++jt) {
        const uint2 v = *(const uint2*)(part + ((size_t)jt * BATCH + b) * D_MODEL + d0);
        const h2 p0 = as_h2(v.x), p1 = as_h2(v.y);
        a0 += (float)p0.x; a1 += (float)p0.y;
        a2 += (float)p1.x; a3 += (float)p1.y;
    }
    *(float4*)(out + (size_t)BATCH * D1 + (size_t)b * D_MODEL + d0) =
        make_float4(a0, a1, a2, a3);
}

// ---------------------------------------------------------------------------
// Fallback (tiny ws): fp32 path, raw strided w1 gather
// ---------------------------------------------------------------------------
__global__ __launch_bounds__(256) void sparse_ff_f32_raw(const int* __restrict__ mask,
                                                         const float* __restrict__ x,
                                                         const float* __restrict__ w1,
                                                         const float* __restrict__ w2,
                                                         const float* __restrict__ b2,
                                                         float* __restrict__ out) {
    __shared__ float x_lds[D_MODEL];
    __shared__ float relu_lds[D1];
    __shared__ int   m_lds[D1];
    const int b = blockIdx.x, t = threadIdx.x;
    const int wave = t >> 6, lane = t & 63;
    *(float4*)&x_lds[t * 4] = *(const float4*)(x + (size_t)b * D_MODEL + t * 4);
    if (t < D1) {
        const int mv = mask[b * D1 + t];
        m_lds[t] = mv;
        out[(size_t)b * D1 + t] = (float)mv;
    }
    __syncthreads();
    for (int jj = 0; jj < 32; ++jj) {
        const int j = wave * 32 + jj;
        const int m = m_lds[j];
        float acc = 0.f;
#pragma unroll
        for (int c = 0; c < 16; ++c) {
            const int d = c * 64 + lane;
            acc = fmaf(w1[(size_t)d * D_FF + j * N_ELEM + m], x_lds[d], acc);
        }
#pragma unroll
        for (int off = 32; off; off >>= 1) acc += __shfl_down(acc, off);
        if (lane == 0) relu_lds[j] = fmaxf(acc, 0.f);
    }
    __syncthreads();
    const int dm0 = t * 4;
    const float4 bv = *(const float4*)(b2 + dm0);
    float a0 = bv.x, a1 = bv.y, a2 = bv.z, a3 = bv.w;
    for (int j = 0; j < D1; ++j) {
        const float r = relu_lds[j];
        if (r > 0.f) {
            const float4 wv = *(const float4*)(w2 + (size_t)(m_lds[j] * D1 + j) * D_MODEL + dm0);
            a0 = fmaf(r, wv.x, a0); a1 = fmaf(r, wv.y, a1);
            a2 = fmaf(r, wv.z, a2); a3 = fmaf(r, wv.w, a3);
        }
    }
    *(float4*)(out + (size_t)BATCH * D1 + (size_t)b * D_MODEL + dm0) =
        make_float4(a0, a1, a2, a3);
}

extern "C" void kernel_launch(void* const* d_in, const int* in_sizes, int n_in,
                              void* d_out, int out_size, void* d_ws, size_t ws_size,
                              hipStream_t stream) {
    const int*   mask = (const int*)d_in[0];
    const float* x    = (const float*)d_in[1];
    const float* w1   = (const float*)d_in[2];
    const float* w2   = (const float*)d_in[3];
    const float* b2   = (const float*)d_in[4];
    float* out = (float*)d_out;

    const size_t w1h_bytes  = (size_t)D_FF * D_MODEL * sizeof(u16);          // 16 MiB
    const size_t w2h_bytes  = (size_t)D_FF * D_MODEL * sizeof(u16);          // 16 MiB
    const size_t part_bytes = (size_t)NJT * BATCH * D_MODEL * sizeof(u16);   // 32 MiB

    if (ws_size >= w1h_bytes + w2h_bytes + part_bytes) {
        u16* w1h  = (u16*)d_ws;
        u16* w2h  = (u16*)((char*)d_ws + w1h_bytes);
        u16* part = (u16*)((char*)d_ws + w1h_bytes + w2h_bytes);
        transpose_cast_w1<<<dim3(D_FF / 64, D_MODEL / 64), 256, 0, stream>>>(w1, w1h);
        cast_w2<<<(D_FF * D_MODEL / 8) / 256, 256, 0, stream>>>(w2, w2h);
        sparse_ff_jt<<<(BATCH / B_T) * NJT, 256, 0, stream>>>(mask, x, w1h, w2h, part);
        reduce_partials<<<BATCH, 256, 0, stream>>>(mask, b2, part, out);
    } else {
        sparse_ff_f32_raw<<<BATCH, 256, 0, stream>>>(mask, x, w1, w2, b2, out);
    }
}